// Round 2
// baseline (878.971 us; speedup 1.0000x reference)
//
#include <hip/hip_runtime.h>
#include <math.h>

#define NEGV (-1e9f)
constexpr int B = 32, S = 4096, K = 512, H = 512;

typedef __attribute__((ext_vector_type(8))) short bf16x8;
typedef __attribute__((ext_vector_type(4))) float f32x4;
typedef __attribute__((ext_vector_type(4))) int i32x4;

__device__ __forceinline__ short f2bf(float x) {
  union { float f; unsigned u; } v; v.f = x;
  unsigned r = (v.u + 0x7FFFu + ((v.u >> 16) & 1u)) >> 16;
  return (short)r;
}

// packed f32x2 -> bf16x2 (RNE), 1 VALU instr for 2 elements (no builtin on gfx950)
__device__ __forceinline__ unsigned cvt_pk_bf16(float lo, float hi) {
  unsigned r;
  asm("v_cvt_pk_bf16_f32 %0, %1, %2" : "=v"(r) : "v"(lo), "v"(hi));
  return r;
}

__device__ __forceinline__ void cvt_store16(short* dst, const float4 a, const float4 b) {
  i32x4 t;
  t[0] = (int)cvt_pk_bf16(a.x, a.y);
  t[1] = (int)cvt_pk_bf16(a.z, a.w);
  t[2] = (int)cvt_pk_bf16(b.x, b.y);
  t[3] = (int)cvt_pk_bf16(b.z, b.w);
  *(i32x4*)dst = t;
}

__device__ __forceinline__ float fast_tanh(float x) {
  // tanh(x) = 1 - 2/(exp(2x)+1); accurate to ~1e-6, saturates correctly
  return 1.f - 2.f / (__expf(2.f * x) + 1.f);
}

// LDS-only barrier: makes ds_write visible without draining vmcnt — global
// prefetch loads stay in flight across it (T4 counted-vmcnt semantics; the
// compiler's own counted vmcnt waits before each register use stay correct).
__device__ __forceinline__ void block_sync_lds() {
  asm volatile("s_waitcnt lgkmcnt(0)" ::: "memory");
  __builtin_amdgcn_s_barrier();
  __builtin_amdgcn_sched_barrier(0);
}

// ---------------- K0: pre-swizzle Wk (f32) -> bf16 MFMA-B-fragment-major layout
// frag f = (c*32 + n)*64 + lane; lane holds B[k=c*32+(lane>>4)*8+j][h=n*16+(lane&15)]
__global__ __launch_bounds__(64)
void wkswizzle_kernel(const float* __restrict__ Wk_a, const float* __restrict__ Wk_b,
                      short* __restrict__ WkT) {
  const int head = blockIdx.y;
  const float* __restrict__ Wk = head ? Wk_b : Wk_a;
  const int cn = blockIdx.x;            // 0..511 : c*32+n
  const int c = cn >> 5, n = cn & 31;
  const int l = threadIdx.x;
  const int kb = c * 32 + ((l >> 4) << 3);
  const int h = n * 16 + (l & 15);
  bf16x8 frag;
#pragma unroll
  for (int j = 0; j < 8; ++j) frag[j] = f2bf(Wk[(size_t)(kb + j) * H + h]);
  *(bf16x8*)(WkT + (size_t)head * 262144 + ((size_t)cn * 64 + l) * 8) = frag;
}

// ---------------- K1: qproj[head][b][h] = query[b] @ Wq_head ----------------
__global__ __launch_bounds__(512)
void qproj_kernel(const float* __restrict__ query,
                  const float* __restrict__ Wq_a,
                  const float* __restrict__ Wq_b,
                  float* __restrict__ qproj) {
  const int b = blockIdx.x, head = blockIdx.y;
  const float* __restrict__ Wq = head ? Wq_b : Wq_a;
  __shared__ float qs[H];
  qs[threadIdx.x] = query[b * H + threadIdx.x];
  __syncthreads();
  const int h = threadIdx.x;
  float acc = 0.f;
#pragma unroll 8
  for (int k = 0; k < H; ++k) acc = fmaf(qs[k], Wq[k * H + h], acc);
  qproj[(head * B + b) * H + h] = acc;
}

// ---------------- K2: scores via bf16 MFMA, full-H block, BK=64.
// Block 512 (8 waves), tile 64s x 512h. Wave w owns h-tiles n = w*4 .. w*4+3.
// Schedule: one LDS-only barrier per chunk (no vmcnt drain!), A-prefetch depth 3
// (issue A(c+3) at iter c, cvt+ds_write A(c+1)) so HBM latency is covered by
// ~2 chunk bodies even at 1 block/CU. LDS lines XOR-swizzled (L^= g|kk<<2) so
// both ds_write_b128 (staging) and ds_read_b128 (frags) are bank-conflict-free.
// B frags stream from L2 (pre-swizzled WkT) straight into VGPRs.
__global__ __launch_bounds__(512, 2)
void scores_mfma_kernel(const float* __restrict__ values_a, const float* __restrict__ values_b,
                        const short* __restrict__ WkT,
                        const float* __restrict__ v_a, const float* __restrict__ v_b,
                        const float* __restrict__ qproj,
                        float* __restrict__ scores) {
  const int head = blockIdx.z, b = blockIdx.y;
  const int s0 = blockIdx.x * 64;
  const float* __restrict__ V  = (head ? values_b : values_a) + (size_t)b * S * K;
  const float* __restrict__ v  = head ? v_b : v_a;
  const float* __restrict__ qp = qproj + (head * B + b) * H;
  const short* __restrict__ wkb = WkT + (size_t)head * 262144;

  __shared__ __align__(16) short Albuf[2][4096];   // 2 x 8 KB : 64 rows x 64 k, swizzled lines
  __shared__ float red[8 * 64];

  const int tid = threadIdx.x;
  const int w = tid >> 6, l = tid & 63;

  // A staging: thread t stages V[s0 + (t>>3)][c*64 + (t&7)*8 .. +7] (one b128 line)
  const int sa = tid >> 3, ka = (tid & 7) * 8;
  const float* const arow = V + (size_t)(s0 + sa) * K + ka;
  // line L = (kk*4 + i)*64 + ((sa&15)|(g<<4)), swizzled L' = L ^ (g | kk<<2)
  const int g_w = (ka >> 3) & 3, kk_w = ka >> 5;
  const int Lw = ((kk_w * 4 + (sa >> 4)) * 64 + ((sa & 15) | (g_w << 4))) ^ (g_w | (kk_w << 2));
  const int aline = Lw * 8;  // shorts
  // reader lane-slot per kk: l ^ ((l>>4)&3) ^ (kk<<2)
  const int rslot0 = l ^ ((l >> 4) & 3);
  const int rslot1 = rslot0 ^ 4;
  // B frags: wave's h-tiles n = w*4 + nl
  const short* const bbase = wkb + ((w * 4) * 64 + l) * 8;

  f32x4 acc[4][4] = {};

  // prolog: issue A(0),A(1),A(2); cvt+store A(0) (compiler waits only its 4 loads)
  float4 pa[3], pb[3];
  pa[0] = *(const float4*)(arow);        pb[0] = *(const float4*)(arow + 4);
  pa[1] = *(const float4*)(arow + 64);   pb[1] = *(const float4*)(arow + 68);
  pa[2] = *(const float4*)(arow + 128);  pb[2] = *(const float4*)(arow + 132);
  cvt_store16(&Albuf[0][aline], pa[0], pb[0]);
  block_sync_lds();

#pragma unroll
  for (int c = 0; c < 8; ++c) {
    // B frag loads for this chunk (both k32 halves) — counted-waited by compiler
    bf16x8 bfr[2][4];
#pragma unroll
    for (int kk = 0; kk < 2; ++kk)
#pragma unroll
      for (int nl = 0; nl < 4; ++nl)
        bfr[kk][nl] = *(const bf16x8*)(bbase + ((2 * c + kk) * 32 + nl) * 512);
    // depth-3 A prefetch: chunk c+3 into the slot freed when A(c) was stored
    if (c < 5) {
      pa[c % 3] = *(const float4*)(arow + (c + 3) * 64);
      pb[c % 3] = *(const float4*)(arow + (c + 3) * 64 + 4);
    }
    // A frags from the swizzled double buffer
    bf16x8 afr[2][4];
#pragma unroll
    for (int i = 0; i < 4; ++i) {
      afr[0][i] = *(const bf16x8*)(&Albuf[c & 1][((0 * 4 + i) * 64 + rslot0) * 8]);
      afr[1][i] = *(const bf16x8*)(&Albuf[c & 1][((1 * 4 + i) * 64 + rslot1) * 8]);
    }
    __builtin_amdgcn_s_setprio(1);
#pragma unroll
    for (int kk = 0; kk < 2; ++kk)
#pragma unroll
      for (int nl = 0; nl < 4; ++nl)
#pragma unroll
        for (int i = 0; i < 4; ++i)
          acc[i][nl] = __builtin_amdgcn_mfma_f32_16x16x32_bf16(afr[kk][i], bfr[kk][nl], acc[i][nl], 0, 0, 0);
    __builtin_amdgcn_s_setprio(0);
    // convert + LDS-write chunk c+1 into the other buffer, then LDS-only barrier
    if (c < 7) {
      cvt_store16(&Albuf[(c & 1) ^ 1][aline], pa[(c + 1) % 3], pb[(c + 1) % 3]);
      block_sync_lds();
    }
  }

  // Epilogue: score[s] = sum_h v[h] * tanh(acc + qp[h]) ; h = (w*4+nl)*16 + (l&15)
  float qpr[4], vr[4];
#pragma unroll
  for (int nl = 0; nl < 4; ++nl) {
    const int h = (w * 4 + nl) * 16 + (l & 15);
    qpr[nl] = qp[h];
    vr[nl] = v[h];
  }
#pragma unroll
  for (int i = 0; i < 4; ++i)
#pragma unroll
    for (int r = 0; r < 4; ++r) {
      float p = 0.f;
#pragma unroll
      for (int nl = 0; nl < 4; ++nl) p = fmaf(vr[nl], fast_tanh(acc[i][nl][r] + qpr[nl]), p);
#pragma unroll
      for (int off = 8; off > 0; off >>= 1) p += __shfl_xor(p, off, 64);
      if ((l & 15) == 0) red[w * 64 + i * 16 + (l >> 4) * 4 + r] = p;
    }
  __syncthreads();
  if (tid < 64) {
    float tot = 0.f;
#pragma unroll
    for (int ww = 0; ww < 8; ++ww) tot += red[ww * 64 + tid];
    scores[((size_t)head * B + b) * S + s0 + tid] = tot;
  }
}

// ---------------- K3: sparsemax ----------------
__device__ __forceinline__ float bred256(float v, const bool is_max, float* lds) {
#pragma unroll
  for (int o = 32; o > 0; o >>= 1) {
    const float t = __shfl_xor(v, o, 64);
    v = is_max ? fmaxf(v, t) : (v + t);
  }
  __syncthreads();                       // protect lds from previous call's readers
  if ((threadIdx.x & 63) == 0) lds[threadIdx.x >> 6] = v;
  __syncthreads();
  return is_max ? fmaxf(fmaxf(lds[0], lds[1]), fmaxf(lds[2], lds[3]))
                : (lds[0] + lds[1]) + (lds[2] + lds[3]);
}

__global__ __launch_bounds__(256)
void sparsemax_kernel(const float* __restrict__ scores,
                      const int* __restrict__ mask_a, const int* __restrict__ mask_b,
                      float* __restrict__ d_out_f) {
  const int b = blockIdx.x, head = blockIdx.y;
  const float* __restrict__ z = scores + ((size_t)head * B + b) * S;
  const int* __restrict__ mask = (head ? mask_b : mask_a) + b * S;
  float* __restrict__ alpha = d_out_f + B * H + (size_t)head * B * S + (size_t)b * S;
  __shared__ float lds[4];
  const int tid = threadIdx.x;
  float e[16];
#pragma unroll
  for (int t = 0; t < 16; ++t) {
    const int s = t * 256 + tid;
    e[t] = mask[s] ? z[s] : NEGV;
  }
  float m = NEGV;
#pragma unroll
  for (int t = 0; t < 16; ++t) m = fmaxf(m, e[t]);
  m = bred256(m, true, lds);
  float lo = m - 1.f, hi = m;
  for (int it = 0; it < 28; ++it) {
    const float mid = 0.5f * (lo + hi);
    float s = 0.f;
#pragma unroll
    for (int t = 0; t < 16; ++t) s += fmaxf(e[t] - mid, 0.f);
    s = bred256(s, false, lds);
    if (s >= 1.f) lo = mid; else hi = mid;
  }
  float cnt = 0.f, sum = 0.f;
#pragma unroll
  for (int t = 0; t < 16; ++t) {
    if (e[t] > lo) { cnt += 1.f; sum += e[t]; }
  }
  cnt = bred256(cnt, false, lds);
  sum = bred256(sum, false, lds);
  const float tau = (sum - 1.f) / cnt;
#pragma unroll
  for (int t = 0; t < 16; ++t) alpha[t * 256 + tid] = fmaxf(e[t] - tau, 0.f);
}

// ---------------- K4: context = alphas @ values, exploiting sparsemax sparsity
__global__ __launch_bounds__(512)
void context_kernel(const float* __restrict__ values_a, const float* __restrict__ values_b,
                    const float* __restrict__ d_out_f, float* __restrict__ ctx) {
  const int b = blockIdx.x, head = blockIdx.y;
  const float* __restrict__ V = (head ? values_b : values_a) + (size_t)b * S * K;
  const float* __restrict__ al = d_out_f + B * H + (size_t)head * B * S + (size_t)b * S;
  __shared__ int cnt;
  __shared__ int sidx[S];
  __shared__ float sal[S];
  if (threadIdx.x == 0) cnt = 0;
  __syncthreads();
  for (int i = threadIdx.x; i < S; i += 512) {
    const float a = al[i];
    if (a > 0.f) { const int p = atomicAdd(&cnt, 1); sidx[p] = i; sal[p] = a; }
  }
  __syncthreads();
  const int n = cnt;
  const int j = threadIdx.x;
  float acc = 0.f;
  for (int t = 0; t < n; ++t) acc = fmaf(sal[t], V[(size_t)sidx[t] * K + j], acc);
  ctx[(head * B + b) * K + j] = acc;
}

// ---------------- K5: gate + candidates + output merge, one block per batch
__global__ __launch_bounds__(512)
void merge_kernel(const float* __restrict__ query, const float* __restrict__ ctx,
                  const float* __restrict__ Wg, const float* __restrict__ bg,
                  const float* __restrict__ Wu_a, const float* __restrict__ bu_a,
                  const float* __restrict__ Wu_b, const float* __restrict__ bu_b,
                  float* __restrict__ att) {
  const int b = blockIdx.x;
  __shared__ float gin[1536];
  __shared__ float lred[16];
  __shared__ float gw[2];
  const int tid = threadIdx.x;
  gin[tid]        = query[b * H + tid];
  gin[512 + tid]  = ctx[(0 * B + b) * K + tid];
  gin[1024 + tid] = ctx[(1 * B + b) * K + tid];
  __syncthreads();
  float p0 = 0.f, p1 = 0.f;
  for (int i = tid; i < 1536; i += 512) {
    const float x = gin[i];
    p0 = fmaf(x, Wg[i * 2 + 0], p0);
    p1 = fmaf(x, Wg[i * 2 + 1], p1);
  }
#pragma unroll
  for (int o = 32; o > 0; o >>= 1) { p0 += __shfl_xor(p0, o, 64); p1 += __shfl_xor(p1, o, 64); }
  if ((tid & 63) == 0) { lred[tid >> 6] = p0; lred[8 + (tid >> 6)] = p1; }
  __syncthreads();
  if (tid == 0) {
    float l0 = bg[0], l1 = bg[1];
    for (int w = 0; w < 8; ++w) { l0 += lred[w]; l1 += lred[8 + w]; }
    const float mx = fmaxf(l0, l1);
    const float e0 = expf(l0 - mx), e1 = expf(l1 - mx);
    gw[0] = e0 / (e0 + e1);
    gw[1] = e1 / (e0 + e1);
  }
  __syncthreads();
  const int h = tid;
  float aa = bu_a[h], ab = bu_b[h];
  for (int i = 0; i < 1024; ++i) aa = fmaf(gin[i], Wu_a[i * H + h], aa);
  for (int i = 0; i < 1024; ++i) {
    const float x = (i < 512) ? gin[i] : gin[i + 512];
    ab = fmaf(x, Wu_b[i * H + h], ab);
  }
  att[b * H + h] = gw[0] * tanhf(aa) + gw[1] * tanhf(ab);
}

extern "C" void kernel_launch(void* const* d_in, const int* in_sizes, int n_in,
                              void* d_out, int out_size, void* d_ws, size_t ws_size,
                              hipStream_t stream) {
  const float* query    = (const float*)d_in[0];
  const float* values_a = (const float*)d_in[1];
  const float* values_b = (const float*)d_in[2];
  const int*   mask_a   = (const int*)d_in[3];
  const int*   mask_b   = (const int*)d_in[4];
  const float* Wk_a = (const float*)d_in[5];
  const float* Wq_a = (const float*)d_in[6];
  const float* v_a  = (const float*)d_in[7];
  const float* Wk_b = (const float*)d_in[8];
  const float* Wq_b = (const float*)d_in[9];
  const float* v_b  = (const float*)d_in[10];
  const float* Wg   = (const float*)d_in[11];
  const float* bg   = (const float*)d_in[12];
  const float* Wu_a = (const float*)d_in[13];
  const float* bu_a = (const float*)d_in[14];
  const float* Wu_b = (const float*)d_in[15];
  const float* bu_b = (const float*)d_in[16];
  float* out = (float*)d_out;

  float* wsf    = (float*)d_ws;
  float* qproj  = wsf;                                   // [2][B][H]    32K f
  float* scores = wsf + 2 * B * H;                       // [2][B][S]   256K f
  float* ctx    = wsf + 2 * B * H + 2 * B * S;           // [2][B][K]    32K f
  short* WkT    = (short*)(wsf + 2 * B * H + 2 * B * S + 2 * B * K);  // 2 x 262144 bf16

  wkswizzle_kernel<<<dim3(512, 2), 64, 0, stream>>>(Wk_a, Wk_b, WkT);
  qproj_kernel<<<dim3(B, 2), 512, 0, stream>>>(query, Wq_a, Wq_b, qproj);
  scores_mfma_kernel<<<dim3(S / 64, B, 2), 512, 0, stream>>>(
      values_a, values_b, WkT, v_a, v_b, qproj, scores);
  sparsemax_kernel<<<dim3(B, 2), 256, 0, stream>>>(scores, mask_a, mask_b, out);
  context_kernel<<<dim3(B, 2), 512, 0, stream>>>(values_a, values_b, out, ctx);
  merge_kernel<<<B, 512, 0, stream>>>(query, ctx, Wg, bg, Wu_a, bu_a, Wu_b, bu_b, out);
}

// Round 3
// 813.017 us; speedup vs baseline: 1.0811x; 1.0811x over previous
//
#include <hip/hip_runtime.h>
#include <math.h>

#define NEGV (-1e9f)
constexpr int B = 32, S = 4096, K = 512, H = 512;

typedef __attribute__((ext_vector_type(8))) short bf16x8;
typedef __attribute__((ext_vector_type(4))) float f32x4;
typedef __attribute__((ext_vector_type(4))) int i32x4;

__device__ __forceinline__ short f2bf(float x) {
  union { float f; unsigned u; } v; v.f = x;
  unsigned r = (v.u + 0x7FFFu + ((v.u >> 16) & 1u)) >> 16;
  return (short)r;
}

// packed f32x2 -> bf16x2 (RNE), 1 VALU instr for 2 elements (no builtin on gfx950)
__device__ __forceinline__ unsigned cvt_pk_bf16(float lo, float hi) {
  unsigned r;
  asm("v_cvt_pk_bf16_f32 %0, %1, %2" : "=v"(r) : "v"(lo), "v"(hi));
  return r;
}

__device__ __forceinline__ void cvt_store16(short* dst, const float4 a, const float4 b) {
  i32x4 t;
  t[0] = (int)cvt_pk_bf16(a.x, a.y);
  t[1] = (int)cvt_pk_bf16(a.z, a.w);
  t[2] = (int)cvt_pk_bf16(b.x, b.y);
  t[3] = (int)cvt_pk_bf16(b.z, b.w);
  *(i32x4*)dst = t;
}

__device__ __forceinline__ float fast_tanh(float x) {
  // tanh(x) = 1 - 2/(exp(2x)+1); accurate to ~1e-6, saturates correctly
  return 1.f - 2.f / (__expf(2.f * x) + 1.f);
}

// LDS-only barrier: makes ds_write visible without draining vmcnt — global
// prefetch loads stay in flight across it. sched_barrier(0) pins the ds_writes
// above and the next phase's loads below (rule #18).
__device__ __forceinline__ void block_sync_lds() {
  asm volatile("s_waitcnt lgkmcnt(0)" ::: "memory");
  __builtin_amdgcn_s_barrier();
  __builtin_amdgcn_sched_barrier(0);
}

// ---------------- K0: pre-swizzle Wk (f32) -> bf16 MFMA-B-fragment-major layout
// frag f = (c*32 + n)*64 + lane; lane holds B[k=c*32+(lane>>4)*8+j][h=n*16+(lane&15)]
__global__ __launch_bounds__(64)
void wkswizzle_kernel(const float* __restrict__ Wk_a, const float* __restrict__ Wk_b,
                      short* __restrict__ WkT) {
  const int head = blockIdx.y;
  const float* __restrict__ Wk = head ? Wk_b : Wk_a;
  const int cn = blockIdx.x;            // 0..511 : c*32+n
  const int c = cn >> 5, n = cn & 31;
  const int l = threadIdx.x;
  const int kb = c * 32 + ((l >> 4) << 3);
  const int h = n * 16 + (l & 15);
  bf16x8 frag;
#pragma unroll
  for (int j = 0; j < 8; ++j) frag[j] = f2bf(Wk[(size_t)(kb + j) * H + h]);
  *(bf16x8*)(WkT + (size_t)head * 262144 + ((size_t)cn * 64 + l) * 8) = frag;
}

// ---------------- K1: qproj[head][b][h] = query[b] @ Wq_head ----------------
__global__ __launch_bounds__(512)
void qproj_kernel(const float* __restrict__ query,
                  const float* __restrict__ Wq_a,
                  const float* __restrict__ Wq_b,
                  float* __restrict__ qproj) {
  const int b = blockIdx.x, head = blockIdx.y;
  const float* __restrict__ Wq = head ? Wq_b : Wq_a;
  __shared__ float qs[H];
  qs[threadIdx.x] = query[b * H + threadIdx.x];
  __syncthreads();
  const int h = threadIdx.x;
  float acc = 0.f;
#pragma unroll 8
  for (int k = 0; k < H; ++k) acc = fmaf(qs[k], Wq[k * H + h], acc);
  qproj[(head * B + b) * H + h] = acc;
}

// ---------------- K2: partial scores via bf16 MFMA.
// 256-thread / 4-wave blocks (occupancy: 64 AGPR acc + ~64 VGPR = 128 -> 4 waves/SIMD),
// tile 64s x 256h (2 h-slabs). Wave w: h-tiles n = hslab*16 + w*4 .. +3.
// Fixes kept from R2: LDS-only barriers (A-prefetch global loads stay in flight
// across them), BK=32 XOR swizzle L' = L ^ g (conflict-free write AND read),
// v_cvt_pk_bf16_f32 staging, setprio around the MFMA cluster.
// New: XCD-aware work swizzle so the two h-slab blocks sharing a V tile land on
// the same XCD's L2 (bijective since 8192 % 8 == 0).
__global__ __launch_bounds__(256, 4)
void scores_mfma_kernel(const float* __restrict__ values_a, const float* __restrict__ values_b,
                        const short* __restrict__ WkT,
                        const float* __restrict__ v_a, const float* __restrict__ v_b,
                        const float* __restrict__ qproj,
                        float* __restrict__ scores_part) {
  // work swizzle: xcd = lin%8 gets contiguous work chunk; hslab toggles fastest
  const int lin = blockIdx.x + 128 * (blockIdx.y + 32 * blockIdx.z);
  const int wk = ((lin & 7) << 10) | (lin >> 3);
  const int hslab = wk & 1;
  const int s0 = ((wk >> 1) & 63) * 64;
  const int b = (wk >> 7) & 31;
  const int head = (wk >> 12) & 1;

  const float* __restrict__ V  = (head ? values_b : values_a) + (size_t)b * S * K;
  const float* __restrict__ v  = head ? v_b : v_a;
  const float* __restrict__ qp = qproj + (head * B + b) * H;
  const short* __restrict__ wkb = WkT + (size_t)head * 262144;

  __shared__ __align__(16) short Albuf[2][2048];   // 2 x 4 KB : 64 rows x 32 k, swizzled lines
  __shared__ float red[4 * 64];

  const int tid = threadIdx.x;
  const int w = tid >> 6, l = tid & 63;

  // A staging: thread t stages V[s0 + (t>>2)][c*32 + (t&3)*8 .. +7] as one swizzled line
  const int sa = tid >> 2, g = tid & 3;
  const float* const arow = V + (size_t)(s0 + sa) * K + g * 8;
  // logical line L = (sa>>4)*64 + ((sa&15)|(g<<4)); phys L' = L ^ g  (g = slot>>4)
  const int Lw = (((sa >> 4) * 64) + ((sa & 15) | (g << 4))) ^ g;
  // reader lane-slot: phys = (i*64 + l) ^ (l>>4)
  const int rs = l ^ (l >> 4);
  // B frags: wave's h-tiles n = hslab*16 + w*4 + nl
  const short* const bbase = wkb + ((size_t)(hslab * 16 + w * 4) * 64 + l) * 8;

  f32x4 acc[4][4] = {};

  // prolog: load + store chunk 0
  float4 p0 = *(const float4*)(arow);
  float4 p1 = *(const float4*)(arow + 4);
  cvt_store16(&Albuf[0][Lw * 8], p0, p1);
  block_sync_lds();

#pragma unroll
  for (int c = 0; c < 16; ++c) {
    // B frag loads for this chunk — counted-waited by compiler, L2-resident
    bf16x8 bfr[4];
#pragma unroll
    for (int nl = 0; nl < 4; ++nl)
      bfr[nl] = *(const bf16x8*)(bbase + ((size_t)(c * 32 + nl)) * 512);
    // prefetch next A granule (global load stays in flight across the barrier)
    if (c < 15) {
      p0 = *(const float4*)(arow + (c + 1) * 32);
      p1 = *(const float4*)(arow + (c + 1) * 32 + 4);
    }
    // A frags from the swizzled buffer
    bf16x8 afr[4];
#pragma unroll
    for (int i = 0; i < 4; ++i)
      afr[i] = *(const bf16x8*)(&Albuf[c & 1][(i * 64 + rs) * 8]);
    __builtin_amdgcn_s_setprio(1);
#pragma unroll
    for (int nl = 0; nl < 4; ++nl)
#pragma unroll
      for (int i = 0; i < 4; ++i)
        acc[i][nl] = __builtin_amdgcn_mfma_f32_16x16x32_bf16(afr[i], bfr[nl], acc[i][nl], 0, 0, 0);
    __builtin_amdgcn_s_setprio(0);
    // convert + LDS-write chunk c+1 into the other buffer, then LDS-only barrier
    if (c < 15) {
      cvt_store16(&Albuf[(c & 1) ^ 1][Lw * 8], p0, p1);
      block_sync_lds();
    }
  }

  // Epilogue: partial_score = sum_{h in slab} v[h] * tanh(acc + qp[h])
  float qpr[4], vr[4];
#pragma unroll
  for (int nl = 0; nl < 4; ++nl) {
    const int h = (hslab * 16 + w * 4 + nl) * 16 + (l & 15);
    qpr[nl] = qp[h];
    vr[nl] = v[h];
  }
#pragma unroll
  for (int i = 0; i < 4; ++i)
#pragma unroll
    for (int r = 0; r < 4; ++r) {
      float p = 0.f;
#pragma unroll
      for (int nl = 0; nl < 4; ++nl) p = fmaf(vr[nl], fast_tanh(acc[i][nl][r] + qpr[nl]), p);
#pragma unroll
      for (int off = 8; off > 0; off >>= 1) p += __shfl_xor(p, off, 64);
      if ((l & 15) == 0) red[w * 64 + i * 16 + (l >> 4) * 4 + r] = p;
    }
  __syncthreads();
  if (tid < 64) {
    const float tot = red[tid] + red[64 + tid] + red[128 + tid] + red[192 + tid];
    scores_part[(((size_t)hslab * 2 + head) * B + b) * S + s0 + tid] = tot;
  }
}

// ---------------- K3: sparsemax (merges hslab partials + mask) ----------------
__device__ __forceinline__ float bred256(float v, const bool is_max, float* lds) {
#pragma unroll
  for (int o = 32; o > 0; o >>= 1) {
    const float t = __shfl_xor(v, o, 64);
    v = is_max ? fmaxf(v, t) : (v + t);
  }
  __syncthreads();                       // protect lds from previous call's readers
  if ((threadIdx.x & 63) == 0) lds[threadIdx.x >> 6] = v;
  __syncthreads();
  return is_max ? fmaxf(fmaxf(lds[0], lds[1]), fmaxf(lds[2], lds[3]))
                : (lds[0] + lds[1]) + (lds[2] + lds[3]);
}

__global__ __launch_bounds__(256)
void sparsemax_kernel(const float* __restrict__ scores_part,
                      const int* __restrict__ mask_a, const int* __restrict__ mask_b,
                      float* __restrict__ d_out_f) {
  const int b = blockIdx.x, head = blockIdx.y;
  const float* __restrict__ z0 = scores_part + (((size_t)0 * 2 + head) * B + b) * S;
  const float* __restrict__ z1 = scores_part + (((size_t)1 * 2 + head) * B + b) * S;
  const int* __restrict__ mask = (head ? mask_b : mask_a) + b * S;
  float* __restrict__ alpha = d_out_f + B * H + (size_t)head * B * S + (size_t)b * S;
  __shared__ float lds[4];
  const int tid = threadIdx.x;
  float e[16];
#pragma unroll
  for (int t = 0; t < 16; ++t) {
    const int s = t * 256 + tid;
    e[t] = mask[s] ? (z0[s] + z1[s]) : NEGV;
  }
  float m = NEGV;
#pragma unroll
  for (int t = 0; t < 16; ++t) m = fmaxf(m, e[t]);
  m = bred256(m, true, lds);
  float lo = m - 1.f, hi = m;
  for (int it = 0; it < 28; ++it) {
    const float mid = 0.5f * (lo + hi);
    float s = 0.f;
#pragma unroll
    for (int t = 0; t < 16; ++t) s += fmaxf(e[t] - mid, 0.f);
    s = bred256(s, false, lds);
    if (s >= 1.f) lo = mid; else hi = mid;
  }
  float cnt = 0.f, sum = 0.f;
#pragma unroll
  for (int t = 0; t < 16; ++t) {
    if (e[t] > lo) { cnt += 1.f; sum += e[t]; }
  }
  cnt = bred256(cnt, false, lds);
  sum = bred256(sum, false, lds);
  const float tau = (sum - 1.f) / cnt;
#pragma unroll
  for (int t = 0; t < 16; ++t) alpha[t * 256 + tid] = fmaxf(e[t] - tau, 0.f);
}

// ---------------- K4: context = alphas @ values, exploiting sparsemax sparsity
__global__ __launch_bounds__(512)
void context_kernel(const float* __restrict__ values_a, const float* __restrict__ values_b,
                    const float* __restrict__ d_out_f, float* __restrict__ ctx) {
  const int b = blockIdx.x, head = blockIdx.y;
  const float* __restrict__ V = (head ? values_b : values_a) + (size_t)b * S * K;
  const float* __restrict__ al = d_out_f + B * H + (size_t)head * B * S + (size_t)b * S;
  __shared__ int cnt;
  __shared__ int sidx[S];
  __shared__ float sal[S];
  if (threadIdx.x == 0) cnt = 0;
  __syncthreads();
  for (int i = threadIdx.x; i < S; i += 512) {
    const float a = al[i];
    if (a > 0.f) { const int p = atomicAdd(&cnt, 1); sidx[p] = i; sal[p] = a; }
  }
  __syncthreads();
  const int n = cnt;
  const int j = threadIdx.x;
  float acc = 0.f;
  for (int t = 0; t < n; ++t) acc = fmaf(sal[t], V[(size_t)sidx[t] * K + j], acc);
  ctx[(head * B + b) * K + j] = acc;
}

// ---------------- K5: gate + candidates + output merge, one block per batch
__global__ __launch_bounds__(512)
void merge_kernel(const float* __restrict__ query, const float* __restrict__ ctx,
                  const float* __restrict__ Wg, const float* __restrict__ bg,
                  const float* __restrict__ Wu_a, const float* __restrict__ bu_a,
                  const float* __restrict__ Wu_b, const float* __restrict__ bu_b,
                  float* __restrict__ att) {
  const int b = blockIdx.x;
  __shared__ float gin[1536];
  __shared__ float lred[16];
  __shared__ float gw[2];
  const int tid = threadIdx.x;
  gin[tid]        = query[b * H + tid];
  gin[512 + tid]  = ctx[(0 * B + b) * K + tid];
  gin[1024 + tid] = ctx[(1 * B + b) * K + tid];
  __syncthreads();
  float p0 = 0.f, p1 = 0.f;
  for (int i = tid; i < 1536; i += 512) {
    const float x = gin[i];
    p0 = fmaf(x, Wg[i * 2 + 0], p0);
    p1 = fmaf(x, Wg[i * 2 + 1], p1);
  }
#pragma unroll
  for (int o = 32; o > 0; o >>= 1) { p0 += __shfl_xor(p0, o, 64); p1 += __shfl_xor(p1, o, 64); }
  if ((tid & 63) == 0) { lred[tid >> 6] = p0; lred[8 + (tid >> 6)] = p1; }
  __syncthreads();
  if (tid == 0) {
    float l0 = bg[0], l1 = bg[1];
    for (int w = 0; w < 8; ++w) { l0 += lred[w]; l1 += lred[8 + w]; }
    const float mx = fmaxf(l0, l1);
    const float e0 = expf(l0 - mx), e1 = expf(l1 - mx);
    gw[0] = e0 / (e0 + e1);
    gw[1] = e1 / (e0 + e1);
  }
  __syncthreads();
  const int h = tid;
  float aa = bu_a[h], ab = bu_b[h];
  for (int i = 0; i < 1024; ++i) aa = fmaf(gin[i], Wu_a[i * H + h], aa);
  for (int i = 0; i < 1024; ++i) {
    const float x = (i < 512) ? gin[i] : gin[i + 512];
    ab = fmaf(x, Wu_b[i * H + h], ab);
  }
  att[b * H + h] = gw[0] * tanhf(aa) + gw[1] * tanhf(ab);
}

extern "C" void kernel_launch(void* const* d_in, const int* in_sizes, int n_in,
                              void* d_out, int out_size, void* d_ws, size_t ws_size,
                              hipStream_t stream) {
  const float* query    = (const float*)d_in[0];
  const float* values_a = (const float*)d_in[1];
  const float* values_b = (const float*)d_in[2];
  const int*   mask_a   = (const int*)d_in[3];
  const int*   mask_b   = (const int*)d_in[4];
  const float* Wk_a = (const float*)d_in[5];
  const float* Wq_a = (const float*)d_in[6];
  const float* v_a  = (const float*)d_in[7];
  const float* Wk_b = (const float*)d_in[8];
  const float* Wq_b = (const float*)d_in[9];
  const float* v_b  = (const float*)d_in[10];
  const float* Wg   = (const float*)d_in[11];
  const float* bg   = (const float*)d_in[12];
  const float* Wu_a = (const float*)d_in[13];
  const float* bu_a = (const float*)d_in[14];
  const float* Wu_b = (const float*)d_in[15];
  const float* bu_b = (const float*)d_in[16];
  float* out = (float*)d_out;

  float* wsf         = (float*)d_ws;
  float* qproj       = wsf;                                   // [2][B][H]      32K f
  float* scores_part = wsf + 2 * B * H;                       // [2][2][B][S]   1M f
  float* ctx         = wsf + 2 * B * H + 4 * B * S;           // [2][B][K]      32K f
  short* WkT         = (short*)(wsf + 2 * B * H + 4 * B * S + 2 * B * K);  // 2 x 262144 bf16

  wkswizzle_kernel<<<dim3(512, 2), 64, 0, stream>>>(Wk_a, Wk_b, WkT);
  qproj_kernel<<<dim3(B, 2), 512, 0, stream>>>(query, Wq_a, Wq_b, qproj);
  scores_mfma_kernel<<<dim3(128, B, 2), 256, 0, stream>>>(
      values_a, values_b, WkT, v_a, v_b, qproj, scores_part);
  sparsemax_kernel<<<dim3(B, 2), 256, 0, stream>>>(scores_part, mask_a, mask_b, out);
  context_kernel<<<dim3(B, 2), 512, 0, stream>>>(values_a, values_b, out, ctx);
  merge_kernel<<<B, 512, 0, stream>>>(query, ctx, Wg, bg, Wu_a, bu_a, Wu_b, bu_b, out);
}